// Round 1
// baseline (97.522 us; speedup 1.0000x reference)
//
#include <hip/hip_runtime.h>
#include <math.h>

#define BROWS 8192
#define WDIM 256
#define NTILES 10        // upper-triangular 64x64 tile pairs of the 4x4 tile grid
#define CHUNKS 25
#define CHUNK_ROWS 336   // 21 stages of 16 rows; last chunk covers 128 rows (8 stages)
#define TILE_ELEMS 4096  // 64*64

static __device__ const int g_tile_ti[NTILES] = {0,0,0,0,1,1,1,2,2,3};
static __device__ const int g_tile_tj[NTILES] = {0,1,2,3,1,2,3,2,3,3};

// ---------------------------------------------------------------- column sums
__global__ __launch_bounds__(256)
void colsum_kernel(const float* __restrict__ E, float* __restrict__ colsum) {
    // 256 blocks x 256 threads; block b handles rows [b*32, b*32+32)
    const int j = threadIdx.x;
    const int r0 = blockIdx.x * 32;
    float s = 0.f;
    #pragma unroll 4
    for (int r = 0; r < 32; ++r) {
        s += E[(size_t)(r0 + r) * WDIM + j];
    }
    atomicAdd(&colsum[j], s);
}

// ------------------------------------------------- Gram partials (split-K)
// grid = (NTILES, CHUNKS); block = 256 threads. Each block computes the
// partial 64x64 tile (ti,tj) over its chunk's rows and stores it to ws.
__global__ __launch_bounds__(256)
void gram_partial_kernel(const float* __restrict__ E, float* __restrict__ partials) {
    const int t = blockIdx.x;
    const int c = blockIdx.y;
    const int ti = g_tile_ti[t], tj = g_tile_tj[t];
    const int tid = threadIdx.x;
    const int tx = tid & 15, ty = tid >> 4;   // compute layout: thread -> 4x4 sub-tile
    const int rr = ty, c4 = tx;               // staging layout: row rr, float4 col c4

    __shared__ __align__(16) float a_s[16][64];
    __shared__ __align__(16) float b_s[16][64];

    const int row0 = c * CHUNK_ROWS;
    const int nrows = min(CHUNK_ROWS, BROWS - row0);
    const int nstages = nrows >> 4;           // always whole 16-row stages

    const float* Ea = E + ti * 64;
    const float* Eb = E + tj * 64;

    float acc[4][4];
    #pragma unroll
    for (int ii = 0; ii < 4; ++ii)
        #pragma unroll
        for (int jj = 0; jj < 4; ++jj) acc[ii][jj] = 0.f;

    // prefetch stage 0 into registers
    float4 pa, pb;
    {
        const size_t r = (size_t)(row0 + rr);
        pa = *(const float4*)(Ea + r * WDIM + c4 * 4);
        pb = *(const float4*)(Eb + r * WDIM + c4 * 4);
    }

    for (int s = 0; s < nstages; ++s) {
        __syncthreads();   // previous stage's LDS reads done
        *(float4*)&a_s[rr][c4 * 4] = pa;
        *(float4*)&b_s[rr][c4 * 4] = pb;
        if (s + 1 < nstages) {
            const size_t r = (size_t)(row0 + (s + 1) * 16 + rr);
            pa = *(const float4*)(Ea + r * WDIM + c4 * 4);
            pb = *(const float4*)(Eb + r * WDIM + c4 * 4);
        }
        __syncthreads();   // stage visible
        #pragma unroll
        for (int k = 0; k < 16; ++k) {
            const float4 a4 = *(const float4*)&a_s[k][ty * 4];
            const float4 b4 = *(const float4*)&b_s[k][tx * 4];
            const float av[4] = {a4.x, a4.y, a4.z, a4.w};
            const float bv[4] = {b4.x, b4.y, b4.z, b4.w};
            #pragma unroll
            for (int ii = 0; ii < 4; ++ii)
                #pragma unroll
                for (int jj = 0; jj < 4; ++jj)
                    acc[ii][jj] = fmaf(av[ii], bv[jj], acc[ii][jj]);
        }
    }

    float* dst = partials + (size_t)(c * NTILES + t) * TILE_ELEMS;
    #pragma unroll
    for (int ii = 0; ii < 4; ++ii) {
        const float4 v = make_float4(acc[ii][0], acc[ii][1], acc[ii][2], acc[ii][3]);
        *(float4*)(dst + (ty * 4 + ii) * 64 + tx * 4) = v;
    }
}

// Fallback variant when ws is too small for partials: atomicAdd into G[256*256]
__global__ __launch_bounds__(256)
void gram_atomic_kernel(const float* __restrict__ E, float* __restrict__ G) {
    const int t = blockIdx.x;
    const int c = blockIdx.y;
    const int ti = g_tile_ti[t], tj = g_tile_tj[t];
    const int tid = threadIdx.x;
    const int tx = tid & 15, ty = tid >> 4;
    const int rr = ty, c4 = tx;

    __shared__ __align__(16) float a_s[16][64];
    __shared__ __align__(16) float b_s[16][64];

    const int row0 = c * CHUNK_ROWS;
    const int nrows = min(CHUNK_ROWS, BROWS - row0);
    const int nstages = nrows >> 4;

    const float* Ea = E + ti * 64;
    const float* Eb = E + tj * 64;

    float acc[4][4];
    #pragma unroll
    for (int ii = 0; ii < 4; ++ii)
        #pragma unroll
        for (int jj = 0; jj < 4; ++jj) acc[ii][jj] = 0.f;

    float4 pa, pb;
    {
        const size_t r = (size_t)(row0 + rr);
        pa = *(const float4*)(Ea + r * WDIM + c4 * 4);
        pb = *(const float4*)(Eb + r * WDIM + c4 * 4);
    }

    for (int s = 0; s < nstages; ++s) {
        __syncthreads();
        *(float4*)&a_s[rr][c4 * 4] = pa;
        *(float4*)&b_s[rr][c4 * 4] = pb;
        if (s + 1 < nstages) {
            const size_t r = (size_t)(row0 + (s + 1) * 16 + rr);
            pa = *(const float4*)(Ea + r * WDIM + c4 * 4);
            pb = *(const float4*)(Eb + r * WDIM + c4 * 4);
        }
        __syncthreads();
        #pragma unroll
        for (int k = 0; k < 16; ++k) {
            const float4 a4 = *(const float4*)&a_s[k][ty * 4];
            const float4 b4 = *(const float4*)&b_s[k][tx * 4];
            const float av[4] = {a4.x, a4.y, a4.z, a4.w};
            const float bv[4] = {b4.x, b4.y, b4.z, b4.w};
            #pragma unroll
            for (int ii = 0; ii < 4; ++ii)
                #pragma unroll
                for (int jj = 0; jj < 4; ++jj)
                    acc[ii][jj] = fmaf(av[ii], bv[jj], acc[ii][jj]);
        }
    }

    #pragma unroll
    for (int ii = 0; ii < 4; ++ii)
        #pragma unroll
        for (int jj = 0; jj < 4; ++jj) {
            const int i = ti * 64 + ty * 4 + ii;
            const int j = tj * 64 + tx * 4 + jj;
            atomicAdd(&G[(size_t)i * WDIM + j], acc[ii][jj]);
        }
}

// ------------------------------------------------------------- finalize loss
__device__ __forceinline__ void finalize_entry(float g, int t, int local,
                                               const float* colsum, float* lossacc,
                                               int tid) {
    const int ti = g_tile_ti[t], tj = g_tile_tj[t];
    const int i = ti * 64 + (local >> 6);
    const int j = tj * 64 + (local & 63);
    const float inv_b = 1.0f / (float)BROWS;
    const float mi = colsum[i] * inv_b;
    const float mj = colsum[j] * inv_b;
    float diff = g * inv_b - mi * mj - ((i == j) ? 1.0f : 0.0f);
    const float w = (ti == tj) ? 1.0f : 2.0f;
    float v = w * diff * diff;
    #pragma unroll
    for (int o = 32; o > 0; o >>= 1) v += __shfl_down(v, o, 64);
    if ((tid & 63) == 0) atomicAdd(lossacc, v);
}

__global__ __launch_bounds__(256)
void finalize_partial_kernel(const float* __restrict__ partials,
                             const float* __restrict__ colsum,
                             float* __restrict__ lossacc) {
    const int e = blockIdx.x * 256 + threadIdx.x;   // 0..40959
    const int t = e >> 12;
    const int local = e & 4095;
    float g = 0.f;
    #pragma unroll 5
    for (int c = 0; c < CHUNKS; ++c)
        g += partials[(size_t)(c * NTILES + t) * TILE_ELEMS + local];
    finalize_entry(g, t, local, colsum, lossacc, threadIdx.x);
}

__global__ __launch_bounds__(256)
void finalize_atomic_kernel(const float* __restrict__ G,
                            const float* __restrict__ colsum,
                            float* __restrict__ lossacc) {
    const int e = blockIdx.x * 256 + threadIdx.x;
    const int t = e >> 12;
    const int local = e & 4095;
    const int ti = g_tile_ti[t], tj = g_tile_tj[t];
    const int i = ti * 64 + (local >> 6);
    const int j = tj * 64 + (local & 63);
    const float g = G[(size_t)i * WDIM + j];
    finalize_entry(g, t, local, colsum, lossacc, threadIdx.x);
}

__global__ void sqrt_kernel(const float* __restrict__ lossacc, float* __restrict__ out) {
    if (threadIdx.x == 0) out[0] = sqrtf(lossacc[0]);
}

// ---------------------------------------------------------------------- host
extern "C" void kernel_launch(void* const* d_in, const int* in_sizes, int n_in,
                              void* d_out, int out_size, void* d_ws, size_t ws_size,
                              hipStream_t stream) {
    const float* E = (const float*)d_in[0];
    // d_in[1] (label) is unused by the reference math.
    float* out = (float*)d_out;
    float* ws = (float*)d_ws;

    float* colsum  = ws;         // 256 floats
    float* lossacc = ws + 256;   // 1 float (padded to 512)
    float* bigbuf  = ws + 512;   // partials or G

    const size_t need_partials = (512 + (size_t)CHUNKS * NTILES * TILE_ELEMS) * sizeof(float);
    const bool use_partials = ws_size >= need_partials;

    if (use_partials) {
        hipMemsetAsync(d_ws, 0, 512 * sizeof(float), stream);
    } else {
        hipMemsetAsync(d_ws, 0, (512 + (size_t)WDIM * WDIM) * sizeof(float), stream);
    }

    colsum_kernel<<<256, 256, 0, stream>>>(E, colsum);

    if (use_partials) {
        gram_partial_kernel<<<dim3(NTILES, CHUNKS), 256, 0, stream>>>(E, bigbuf);
        finalize_partial_kernel<<<160, 256, 0, stream>>>(bigbuf, colsum, lossacc);
    } else {
        gram_atomic_kernel<<<dim3(NTILES, CHUNKS), 256, 0, stream>>>(E, bigbuf);
        finalize_atomic_kernel<<<160, 256, 0, stream>>>(bigbuf, colsum, lossacc);
    }

    sqrt_kernel<<<1, 64, 0, stream>>>(lossacc, out);
}

// Round 2
// 82.363 us; speedup vs baseline: 1.1840x; 1.1840x over previous
//
#include <hip/hip_runtime.h>
#include <math.h>

#define BROWS 8192
#define WDIM 256
#define NTILES 10        // upper-triangular 64x64 tile pairs of the 4x4 tile grid
#define CHUNKS 64        // split-K chunks; 64*128 = 8192 exactly (no remainder)
#define CHUNK_ROWS 128
#define NSTAGES 8        // CHUNK_ROWS / 16
#define TILE_ELEMS 4096  // 64*64
#define FIN_BLOCKS 160   // 160*256 = 40960 = NTILES*TILE_ELEMS

static __device__ const int g_tile_ti[NTILES] = {0,0,0,0,1,1,1,2,2,3};
static __device__ const int g_tile_tj[NTILES] = {0,1,2,3,1,2,3,2,3,3};

// ws layout (floats): [0..255] colsum | [256] lossacc | [257] done(u32) | [512..] partials

// ---------------------------------------------------- Gram partials + colsum
// grid = (NTILES, CHUNKS), block = 256. Block (t,c): partial 64x64 tile over
// 128 rows -> ws. Diagonal-tile blocks (ti==tj) also accumulate the column
// sums of their 64-col slice (they already load exactly those values).
__global__ __launch_bounds__(256)
void gram_kernel(const float* __restrict__ E, float* __restrict__ ws) {
    float* colsum   = ws;
    float* partials = ws + 512;

    const int t = blockIdx.x;
    const int c = blockIdx.y;
    const int ti = g_tile_ti[t], tj = g_tile_tj[t];
    const int tid = threadIdx.x;
    const int tx = tid & 15, ty = tid >> 4;   // ty: stage row / acc row-group; tx: f4 col / acc col-group

    __shared__ __align__(16) float a_s[16][64];
    __shared__ __align__(16) float b_s[16][64];

    const int row0 = c * CHUNK_ROWS;
    const float* Ea = E + ti * 64;
    const float* Eb = E + tj * 64;

    float acc[4][4];
    #pragma unroll
    for (int ii = 0; ii < 4; ++ii)
        #pragma unroll
        for (int jj = 0; jj < 4; ++jj) acc[ii][jj] = 0.f;
    float4 cs = make_float4(0.f, 0.f, 0.f, 0.f);

    // prefetch stage 0
    float4 pa, pb;
    {
        const size_t r = (size_t)(row0 + ty);
        pa = *(const float4*)(Ea + r * WDIM + tx * 4);
        pb = *(const float4*)(Eb + r * WDIM + tx * 4);
    }

    for (int s = 0; s < NSTAGES; ++s) {
        __syncthreads();                       // previous stage's LDS reads done
        *(float4*)&a_s[ty][tx * 4] = pa;
        *(float4*)&b_s[ty][tx * 4] = pb;
        cs.x += pa.x; cs.y += pa.y; cs.z += pa.z; cs.w += pa.w;  // colsum partial
        if (s + 1 < NSTAGES) {
            const size_t r = (size_t)(row0 + (s + 1) * 16 + ty);
            pa = *(const float4*)(Ea + r * WDIM + tx * 4);
            pb = *(const float4*)(Eb + r * WDIM + tx * 4);
        }
        __syncthreads();                       // stage visible
        #pragma unroll
        for (int k = 0; k < 16; ++k) {
            const float4 a4 = *(const float4*)&a_s[k][ty * 4];  // broadcast (free)
            const float4 b4 = *(const float4*)&b_s[k][tx * 4];  // 2-way (free, m136)
            const float av[4] = {a4.x, a4.y, a4.z, a4.w};
            const float bv[4] = {b4.x, b4.y, b4.z, b4.w};
            #pragma unroll
            for (int ii = 0; ii < 4; ++ii)
                #pragma unroll
                for (int jj = 0; jj < 4; ++jj)
                    acc[ii][jj] = fmaf(av[ii], bv[jj], acc[ii][jj]);
        }
    }

    float* dst = partials + (size_t)(c * NTILES + t) * TILE_ELEMS;
    #pragma unroll
    for (int ii = 0; ii < 4; ++ii) {
        const float4 v = make_float4(acc[ii][0], acc[ii][1], acc[ii][2], acc[ii][3]);
        *(float4*)(dst + (ty * 4 + ii) * 64 + tx * 4) = v;
    }

    if (ti == tj) {                            // block-uniform branch
        __syncthreads();                       // k-loop reads of a_s are done
        *(float4*)&a_s[ty][tx * 4] = cs;
        __syncthreads();
        if (tid < 64) {
            float s = 0.f;
            #pragma unroll
            for (int r = 0; r < 16; ++r) s += a_s[r][tid];
            atomicAdd(&colsum[ti * 64 + tid], s);   // 64 atomics/chunk/slice
        }
    }
}

// ----------------------------------------------- finalize loss + sqrt fused
__global__ __launch_bounds__(256)
void finalize_kernel(float* __restrict__ ws, float* __restrict__ out) {
    const float* colsum   = ws;
    float* lossacc        = ws + 256;
    unsigned* done        = (unsigned*)(ws + 257);
    const float* partials = ws + 512;

    const int e = blockIdx.x * 256 + threadIdx.x;   // 0..40959
    const int t = e >> 12;
    const int local = e & 4095;
    const int ti = g_tile_ti[t], tj = g_tile_tj[t];
    const int i = ti * 64 + (local >> 6);
    const int j = tj * 64 + (local & 63);

    float g = 0.f;
    #pragma unroll 8
    for (int c = 0; c < CHUNKS; ++c)
        g += partials[(size_t)(c * NTILES + t) * TILE_ELEMS + local];

    const float inv_b = 1.0f / (float)BROWS;
    const float mi = colsum[i] * inv_b;
    const float mj = colsum[j] * inv_b;
    const float diff = g * inv_b - mi * mj - ((i == j) ? 1.0f : 0.0f);
    float v = ((ti == tj) ? 1.0f : 2.0f) * diff * diff;

    #pragma unroll
    for (int o = 32; o > 0; o >>= 1) v += __shfl_down(v, o, 64);

    __shared__ float red[4];
    if ((threadIdx.x & 63) == 0) red[threadIdx.x >> 6] = v;
    __syncthreads();
    if (threadIdx.x == 0) {
        const float s = red[0] + red[1] + red[2] + red[3];
        atomicAdd(lossacc, s);
        __threadfence();
        const unsigned old = atomicAdd(done, 1u);
        if (old == FIN_BLOCKS - 1) {
            // all 160 lossacc adds happened-before their done increments
            const float total = atomicAdd(lossacc, 0.0f);  // atomic read
            out[0] = sqrtf(total);
        }
    }
}

// ---------------------------------------------------------------------- host
extern "C" void kernel_launch(void* const* d_in, const int* in_sizes, int n_in,
                              void* d_out, int out_size, void* d_ws, size_t ws_size,
                              hipStream_t stream) {
    const float* E = (const float*)d_in[0];
    // d_in[1] (label) is unused by the reference math.
    float* out = (float*)d_out;
    float* ws = (float*)d_ws;

    hipMemsetAsync(d_ws, 0, 512 * sizeof(float), stream);  // colsum + lossacc + done
    gram_kernel<<<dim3(NTILES, CHUNKS), 256, 0, stream>>>(E, ws);
    finalize_kernel<<<FIN_BLOCKS, 256, 0, stream>>>(ws, out);
}